// Round 1
// baseline (13618.712 us; speedup 1.0000x reference)
//
#include <hip/hip_runtime.h>
#include <math.h>

#define T_SEQ 256
#define C_DIM 512
#define D_DIM 1024
#define BN_TOT 320
#define NHEAD 4
#define DHEAD 128
#define QKV_N 1536
#define EPS 1e-5f
#define ATT_SCALE 0.08838834764831845f

// ---------------- prep: W_emb (C,D,3) -> Wc[s][d][c]; c1_W (32,512) -> Wc1t[k][n] ----
__global__ void prep_wc(const float* __restrict__ W_emb, float* __restrict__ Wc) {
  int idx = blockIdx.x * 256 + threadIdx.x;
  if (idx >= 3 * D_DIM * C_DIM) return;
  int c = idx & (C_DIM - 1);
  int d = (idx >> 9) & (D_DIM - 1);
  int s = idx >> 19;
  Wc[idx] = W_emb[(c * D_DIM + d) * 3 + s];
}

__global__ void prep_c1t(const float* __restrict__ c1W, float* __restrict__ Wt) {
  int idx = blockIdx.x * 256 + threadIdx.x;
  if (idx >= C_DIM * 32) return;
  int n = idx & 31;
  int k = idx >> 5;
  Wt[idx] = c1W[n * C_DIM + k];
}

// ---------------- conv1d(k=3,pad=1) as 3 shifted GEMMs, fused ReLU+bias --------------
__launch_bounds__(256)
__global__ void conv_kernel(const float* __restrict__ x, const float* __restrict__ Wc,
                            const float* __restrict__ bias, float* __restrict__ h) {
  __shared__ __align__(16) float As[16][68];
  __shared__ __align__(16) float Bs[16][68];
  int tid = threadIdx.x;
  int tx = tid & 15, ty = tid >> 4;
  int c0 = blockIdx.x * 64, t0 = blockIdx.y * 64, bn = blockIdx.z;
  int arow = tid >> 2, akg = (tid & 3) * 4;
  int brow = tid >> 4, bng = (tid & 15) * 4;
  float acc[4][4] = {};
  for (int s = 0; s < 3; ++s) {
    int tsrc = t0 + arow + s - 1;
    bool valid = (tsrc >= 0) && (tsrc < T_SEQ);
    const float* xa = x + ((size_t)bn * T_SEQ + (valid ? tsrc : 0)) * D_DIM;
    const float* wb = Wc + (size_t)s * D_DIM * C_DIM + c0;
    for (int kd = 0; kd < D_DIM; kd += 16) {
      float4 av = valid ? *(const float4*)(xa + kd + akg) : make_float4(0.f, 0.f, 0.f, 0.f);
      float4 bv = *(const float4*)(wb + (size_t)(kd + brow) * C_DIM + bng);
      __syncthreads();
      As[akg + 0][arow] = av.x; As[akg + 1][arow] = av.y;
      As[akg + 2][arow] = av.z; As[akg + 3][arow] = av.w;
      *(float4*)&Bs[brow][bng] = bv;
      __syncthreads();
#pragma unroll
      for (int k = 0; k < 16; ++k) {
        float4 a4 = *(const float4*)&As[k][ty * 4];
        float4 b4 = *(const float4*)&Bs[k][tx * 4];
        float a[4] = {a4.x, a4.y, a4.z, a4.w};
        float b[4] = {b4.x, b4.y, b4.z, b4.w};
#pragma unroll
        for (int i = 0; i < 4; i++)
#pragma unroll
          for (int j = 0; j < 4; j++) acc[i][j] = fmaf(a[i], b[j], acc[i][j]);
      }
    }
  }
#pragma unroll
  for (int i = 0; i < 4; i++) {
    int t = t0 + ty * 4 + i;
    float* hp = h + ((size_t)bn * T_SEQ + t) * C_DIM + c0 + tx * 4;
#pragma unroll
    for (int j = 0; j < 4; j++) {
      float v = acc[i][j] + bias[c0 + tx * 4 + j];
      hp[j] = fmaxf(v, 0.f);
    }
  }
}

// ---------------- generic fp32 GEMM: C[M,N] = epi(A[M,K] @ B[K,N]) -------------------
// EPI: 0=store, 1=store+bias, 2=C+=acc+bias, 3=gelu(acc+bias)
template <int NT, int EPI>
__launch_bounds__(256)
__global__ void gemm_f32(const float* __restrict__ A, const float* __restrict__ B,
                         float* __restrict__ C, const float* __restrict__ bias,
                         int M, int N, int K) {
  __shared__ __align__(16) float As[16][68];
  __shared__ __align__(16) float Bs[16][NT + 4];
  int tid = threadIdx.x;
  int tx = tid & 15, ty = tid >> 4;
  int n0 = blockIdx.x * NT, m0 = blockIdx.y * 64;
  constexpr int TN = NT / 16;
  float acc[4][TN] = {};
  int arow = tid >> 2, akg = (tid & 3) * 4;
  int bk, bng;
  if (NT == 64) { bk = tid >> 4; bng = (tid & 15) * 4; }
  else          { bk = tid >> 3; bng = (tid & 7) * 4; }
  bool bload = (NT == 64) || (tid < 128);
  const float* Ap = A + (size_t)(m0 + arow) * K + akg;
  const float* Bp = B + (size_t)bk * N + n0 + bng;
  for (int k0 = 0; k0 < K; k0 += 16) {
    float4 av = *(const float4*)(Ap + k0);
    float4 bv = make_float4(0.f, 0.f, 0.f, 0.f);
    if (bload) bv = *(const float4*)(Bp + (size_t)k0 * N);
    __syncthreads();
    As[akg + 0][arow] = av.x; As[akg + 1][arow] = av.y;
    As[akg + 2][arow] = av.z; As[akg + 3][arow] = av.w;
    if (bload) *(float4*)&Bs[bk][bng] = bv;
    __syncthreads();
#pragma unroll
    for (int k = 0; k < 16; ++k) {
      float4 a4 = *(const float4*)&As[k][ty * 4];
      float a[4] = {a4.x, a4.y, a4.z, a4.w};
      float b[TN];
#pragma unroll
      for (int j = 0; j < TN; j++) b[j] = Bs[k][tx * TN + j];
#pragma unroll
      for (int i = 0; i < 4; i++)
#pragma unroll
        for (int j = 0; j < TN; j++) acc[i][j] = fmaf(a[i], b[j], acc[i][j]);
    }
  }
#pragma unroll
  for (int i = 0; i < 4; i++) {
    size_t row = m0 + ty * 4 + i;
    float* Cp = C + row * (size_t)N + n0 + tx * TN;
#pragma unroll
    for (int j = 0; j < TN; j++) {
      float v = acc[i][j];
      if (EPI >= 1) v += bias[n0 + tx * TN + j];
      if (EPI == 2) v += Cp[j];
      if (EPI == 3) v = v * 0.5f * (1.f + erff(v * 0.70710678118f));
      Cp[j] = v;
    }
  }
}

// ---------------- LayerNorm over last dim (512) --------------------------------------
__launch_bounds__(256)
__global__ void ln_kernel(const float* __restrict__ h, const float* __restrict__ g,
                          const float* __restrict__ b, float* __restrict__ u) {
  int row = blockIdx.x;
  int tid = threadIdx.x;
  const float* hp = h + (size_t)row * C_DIM;
  float v0 = hp[tid], v1 = hp[tid + 256];
  __shared__ float red[4];
  __shared__ float stat[2];
  float s = v0 + v1;
#pragma unroll
  for (int o = 32; o > 0; o >>= 1) s += __shfl_down(s, o);
  if ((tid & 63) == 0) red[tid >> 6] = s;
  __syncthreads();
  if (tid == 0) stat[0] = (red[0] + red[1] + red[2] + red[3]) * (1.f / 512.f);
  __syncthreads();
  float mu = stat[0];
  float d0 = v0 - mu, d1 = v1 - mu;
  float q = d0 * d0 + d1 * d1;
#pragma unroll
  for (int o = 32; o > 0; o >>= 1) q += __shfl_down(q, o);
  if ((tid & 63) == 0) red[tid >> 6] = q;
  __syncthreads();
  if (tid == 0) stat[1] = rsqrtf((red[0] + red[1] + red[2] + red[3]) * (1.f / 512.f) + EPS);
  __syncthreads();
  float rs = stat[1];
  float* up = u + (size_t)row * C_DIM;
  up[tid] = d0 * rs * g[tid] + b[tid];
  up[tid + 256] = d1 * rs * g[tid + 256] + b[tid + 256];
}

// ---------------- fused attention per (q-tile, head, bn) -----------------------------
__launch_bounds__(256)
__global__ void attn_kernel(const float* __restrict__ qkv, float* __restrict__ o, int bn_base) {
  __shared__ float Qs[64][132];
  __shared__ float KVs[64][129];
  __shared__ float S[64][260];
  int tid = threadIdx.x;
  int tx = tid & 15, ty = tid >> 4;
  int q0 = blockIdx.x * 64;
  int hh = blockIdx.y;
  int bl = blockIdx.z;
  const float* base = qkv + (size_t)bl * T_SEQ * QKV_N;
#pragma unroll
  for (int it = 0; it < 8; ++it) {
    int idx = tid + it * 256;
    int r = idx >> 5, cg = (idx & 31) * 4;
    float4 v = *(const float4*)(base + (size_t)(q0 + r) * QKV_N + hh * DHEAD + cg);
    Qs[r][cg] = v.x; Qs[r][cg + 1] = v.y; Qs[r][cg + 2] = v.z; Qs[r][cg + 3] = v.w;
  }
  for (int kt = 0; kt < 4; ++kt) {
    __syncthreads();
#pragma unroll
    for (int it = 0; it < 8; ++it) {
      int idx = tid + it * 256;
      int r = idx >> 5, cg = (idx & 31) * 4;
      float4 v = *(const float4*)(base + (size_t)(kt * 64 + r) * QKV_N + C_DIM + hh * DHEAD + cg);
      KVs[r][cg] = v.x; KVs[r][cg + 1] = v.y; KVs[r][cg + 2] = v.z; KVs[r][cg + 3] = v.w;
    }
    __syncthreads();
    float acc[4][4] = {};
#pragma unroll 4
    for (int d = 0; d < DHEAD; ++d) {
      float a[4], b[4];
#pragma unroll
      for (int i = 0; i < 4; i++) a[i] = Qs[ty * 4 + i][d];
#pragma unroll
      for (int j = 0; j < 4; j++) b[j] = KVs[tx * 4 + j][d];
#pragma unroll
      for (int i = 0; i < 4; i++)
#pragma unroll
        for (int j = 0; j < 4; j++) acc[i][j] = fmaf(a[i], b[j], acc[i][j]);
    }
#pragma unroll
    for (int i = 0; i < 4; i++)
#pragma unroll
      for (int j = 0; j < 4; j++)
        S[ty * 4 + i][kt * 64 + tx * 4 + j] = acc[i][j] * ATT_SCALE;
  }
  __syncthreads();
  {
    int r = tid >> 2, p = tid & 3;
    float mx = -1e30f;
#pragma unroll 8
    for (int j = 0; j < 64; j++) mx = fmaxf(mx, S[r][p * 64 + j]);
    mx = fmaxf(mx, __shfl_xor(mx, 1));
    mx = fmaxf(mx, __shfl_xor(mx, 2));
    float sum = 0.f;
#pragma unroll 8
    for (int j = 0; j < 64; j++) {
      float e = expf(S[r][p * 64 + j] - mx);
      S[r][p * 64 + j] = e;
      sum += e;
    }
    sum += __shfl_xor(sum, 1);
    sum += __shfl_xor(sum, 2);
    float inv = 1.f / sum;
#pragma unroll 8
    for (int j = 0; j < 64; j++) S[r][p * 64 + j] *= inv;
  }
  float oacc[4][8] = {};
  for (int kt = 0; kt < 4; ++kt) {
    __syncthreads();
#pragma unroll
    for (int it = 0; it < 8; ++it) {
      int idx = tid + it * 256;
      int r = idx >> 5, cg = (idx & 31) * 4;
      float4 v = *(const float4*)(base + (size_t)(kt * 64 + r) * QKV_N + 2 * C_DIM + hh * DHEAD + cg);
      KVs[r][cg] = v.x; KVs[r][cg + 1] = v.y; KVs[r][cg + 2] = v.z; KVs[r][cg + 3] = v.w;
    }
    __syncthreads();
#pragma unroll 4
    for (int kk = 0; kk < 64; kk++) {
      float p4[4], b[8];
#pragma unroll
      for (int i = 0; i < 4; i++) p4[i] = S[ty * 4 + i][kt * 64 + kk];
#pragma unroll
      for (int j = 0; j < 8; j++) b[j] = KVs[kk][tx * 8 + j];
#pragma unroll
      for (int i = 0; i < 4; i++)
#pragma unroll
        for (int j = 0; j < 8; j++) oacc[i][j] = fmaf(p4[i], b[j], oacc[i][j]);
    }
  }
  int bn = bn_base + bl;
#pragma unroll
  for (int i = 0; i < 4; i++) {
    float* op = o + ((size_t)bn * T_SEQ + q0 + ty * 4 + i) * C_DIM + hh * DHEAD + tx * 8;
#pragma unroll
    for (int j = 0; j < 8; j++) op[j] = oacc[i][j];
  }
}

// ---------------- NormalHead (after x1 GEMM): d1, bn1+relu, x2, d2, bn2+relu, score --
__global__ void head_kernel(const float* __restrict__ x1,
                            const float* __restrict__ bn1g, const float* __restrict__ bn1b,
                            const float* __restrict__ bn1rm, const float* __restrict__ bn1rv,
                            const float* __restrict__ c2W, const float* __restrict__ c2b,
                            const float* __restrict__ bn2g, const float* __restrict__ bn2b,
                            const float* __restrict__ bn2rm, const float* __restrict__ bn2rv,
                            const float* __restrict__ c3W, const float* __restrict__ c3b,
                            float* __restrict__ d1a, float* __restrict__ d2a, float* __restrict__ sca) {
  int r = blockIdx.x * 256 + threadIdx.x;
  if (r >= BN_TOT * T_SEQ) return;
  const float* xp = x1 + (size_t)r * 32;
  float y[32];
  float d1 = 0.f;
#pragma unroll
  for (int oc = 0; oc < 32; oc++) {
    float v = xp[oc];
    float dm = v - bn1rm[oc];
    d1 += dm * dm / bn1rv[oc];
    float t = dm * rsqrtf(bn1rv[oc] + EPS) * bn1g[oc] + bn1b[oc];
    y[oc] = fmaxf(t, 0.f);
  }
  float d2 = 0.f, sacc = 0.f;
#pragma unroll
  for (int o2 = 0; o2 < 16; o2++) {
    float s2 = 0.f;
#pragma unroll
    for (int oc = 0; oc < 32; oc++) s2 = fmaf(y[oc], c2W[o2 * 32 + oc], s2);
    s2 += c2b[o2];
    float dm = s2 - bn2rm[o2];
    d2 += dm * dm / bn2rv[o2];
    float t = dm * rsqrtf(bn2rv[o2] + EPS) * bn2g[o2] + bn2b[o2];
    t = fmaxf(t, 0.f);
    sacc = fmaf(t, c3W[o2], sacc);
  }
  float sc = 1.f / (1.f + expf(-(sacc + c3b[0])));
  d1a[r] = sqrtf(d1);
  d2a[r] = sqrtf(d2);
  sca[r] = sc;
}

__global__ void reduce_kernel(const float* __restrict__ d1a, const float* __restrict__ d2a,
                              const float* __restrict__ sca, float* __restrict__ out) {
  int idx = blockIdx.x * 256 + threadIdx.x;
  if (idx >= 32 * T_SEQ) return;
  int b = idx >> 8, t = idx & 255;
  float s1 = 0.f, s2 = 0.f, ss = 0.f;
  for (int n = 0; n < 10; n++) {
    int r = (b * 10 + n) * T_SEQ + t;
    s1 += d1a[r];
    s2 += d2a[r];
    ss += sca[r];
  }
  out[idx] = (s1 + s2) * ss * 0.01f;
}

extern "C" void kernel_launch(void* const* d_in, const int* in_sizes, int n_in,
                              void* d_out, int out_size, void* d_ws, size_t ws_size,
                              hipStream_t stream) {
  const float* x     = (const float*)d_in[0];
  const float* Wemb  = (const float*)d_in[1];
  const float* bemb  = (const float*)d_in[2];
  const float* ln1g  = (const float*)d_in[3];
  const float* ln1b  = (const float*)d_in[4];
  const float* Wqkv  = (const float*)d_in[5];
  const float* Wo    = (const float*)d_in[6];
  const float* bo    = (const float*)d_in[7];
  const float* ln2g  = (const float*)d_in[8];
  const float* ln2b  = (const float*)d_in[9];
  const float* W1    = (const float*)d_in[10];
  const float* b1    = (const float*)d_in[11];
  const float* W2    = (const float*)d_in[12];
  const float* b2    = (const float*)d_in[13];
  const float* c1W   = (const float*)d_in[14];
  const float* c1b   = (const float*)d_in[15];
  const float* bn1g  = (const float*)d_in[16];
  const float* bn1b  = (const float*)d_in[17];
  const float* bn1rm = (const float*)d_in[18];
  const float* bn1rv = (const float*)d_in[19];
  const float* c2W   = (const float*)d_in[20];
  const float* c2b   = (const float*)d_in[21];
  const float* bn2g  = (const float*)d_in[22];
  const float* bn2b  = (const float*)d_in[23];
  const float* bn2rm = (const float*)d_in[24];
  const float* bn2rv = (const float*)d_in[25];
  const float* c3W   = (const float*)d_in[26];
  const float* c3b   = (const float*)d_in[27];

  char* w = (char*)d_ws;
  size_t off = 0;
  auto alloc = [&](size_t nfloats) {
    float* p = (float*)(w + off);
    off += ((nfloats * 4 + 255) / 256) * 256;
    return p;
  };
  float* h    = alloc((size_t)BN_TOT * T_SEQ * C_DIM);   // 168 MB
  float* u    = alloc((size_t)BN_TOT * T_SEQ * C_DIM);   // 168 MB (LN out / attn out / gelu in)
  float* qkvb = alloc((size_t)80 * T_SEQ * QKV_N);       // 126 MB (qkv chunk / mlp mid)
  float* Wc   = alloc((size_t)3 * D_DIM * C_DIM);
  float* Wc1t = alloc((size_t)C_DIM * 32);
  float* x1   = alloc((size_t)BN_TOT * T_SEQ * 32);
  float* d1a  = alloc((size_t)BN_TOT * T_SEQ);
  float* d2a  = alloc((size_t)BN_TOT * T_SEQ);
  float* sca  = alloc((size_t)BN_TOT * T_SEQ);

  prep_wc<<<(3 * D_DIM * C_DIM + 255) / 256, 256, 0, stream>>>(Wemb, Wc);
  prep_c1t<<<(C_DIM * 32 + 255) / 256, 256, 0, stream>>>(c1W, Wc1t);
  conv_kernel<<<dim3(8, 4, BN_TOT), 256, 0, stream>>>(x, Wc, bemb, h);

  for (int l = 0; l < 2; ++l) {
    ln_kernel<<<BN_TOT * T_SEQ, 256, 0, stream>>>(h, ln1g + l * C_DIM, ln1b + l * C_DIM, u);
    for (int c = 0; c < 4; ++c) {
      gemm_f32<64, 0><<<dim3(QKV_N / 64, 20480 / 64), 256, 0, stream>>>(
          u + (size_t)c * 20480 * C_DIM, Wqkv + (size_t)l * C_DIM * QKV_N, qkvb, nullptr,
          20480, QKV_N, C_DIM);
      attn_kernel<<<dim3(4, NHEAD, 80), 256, 0, stream>>>(qkvb, u, c * 80);
    }
    gemm_f32<64, 2><<<dim3(C_DIM / 64, 81920 / 64), 256, 0, stream>>>(
        u, Wo + (size_t)l * C_DIM * C_DIM, h, bo + l * C_DIM, 81920, C_DIM, C_DIM);
    ln_kernel<<<BN_TOT * T_SEQ, 256, 0, stream>>>(h, ln2g + l * C_DIM, ln2b + l * C_DIM, u);
    for (int c = 0; c < 2; ++c) {
      gemm_f32<64, 3><<<dim3(C_DIM / 64, 40960 / 64), 256, 0, stream>>>(
          u + (size_t)c * 40960 * C_DIM, W1 + (size_t)l * C_DIM * C_DIM, qkvb, b1 + l * C_DIM,
          40960, C_DIM, C_DIM);
      gemm_f32<64, 2><<<dim3(C_DIM / 64, 40960 / 64), 256, 0, stream>>>(
          qkvb, W2 + (size_t)l * C_DIM * C_DIM, h + (size_t)c * 40960 * C_DIM, b2 + l * C_DIM,
          40960, C_DIM, C_DIM);
    }
  }

  gemm_f32<32, 1><<<dim3(1, 81920 / 64), 256, 0, stream>>>(h, Wc1t, x1, c1b, 81920, 32, C_DIM);
  head_kernel<<<(BN_TOT * T_SEQ + 255) / 256, 256, 0, stream>>>(
      x1, bn1g, bn1b, bn1rm, bn1rv, c2W, c2b, bn2g, bn2b, bn2rm, bn2rv, c3W, c3b, d1a, d2a, sca);
  reduce_kernel<<<32, 256, 0, stream>>>(d1a, d2a, sca, (float*)d_out);
}

// Round 2
// 5525.323 us; speedup vs baseline: 2.4648x; 2.4648x over previous
//
#include <hip/hip_runtime.h>
#include <math.h>

#define T_SEQ 256
#define C_DIM 512
#define D_DIM 1024
#define BN_TOT 320
#define NHEAD 4
#define DHEAD 128
#define QKV_N 1536
#define EPS 1e-5f
#define ATT_SCALE 0.08838834764831845f

typedef unsigned short u16;
typedef unsigned int u32;
typedef __attribute__((ext_vector_type(8))) short bf16x8;
typedef __attribute__((ext_vector_type(4))) float f32x4;

__device__ __forceinline__ u16 f2bf(float f) {
  union { float f; u32 u; } v; v.f = f;
  u32 r = v.u + 0x7fffu + ((v.u >> 16) & 1u);
  return (u16)(r >> 16);
}

__device__ __forceinline__ void gload_lds16(const u16* g, u16* l) {
  __builtin_amdgcn_global_load_lds((const __attribute__((address_space(1))) u32*)g,
                                   (__attribute__((address_space(3))) u32*)l, 16, 0, 0);
}

// ---------------- prep kernels -------------------------------------------------------
// xpad[bn][258][1024] bf16, rows 0 and 257 zero (conv padding)
__global__ void convert_x(const float* __restrict__ x, u16* __restrict__ xpad) {
  size_t idx = (size_t)blockIdx.x * 256 + threadIdx.x;
  if (idx >= (size_t)BN_TOT * 258 * 1024) return;
  size_t row = idx >> 10; int col = idx & 1023;
  int bn = (int)(row / 258), tr = (int)(row % 258);
  float v = (tr == 0 || tr == 257) ? 0.f : x[((size_t)bn * 256 + tr - 1) * 1024 + col];
  xpad[idx] = f2bf(v);
}

// Wct[s][c][d] bf16 from W_emb[c][d][s]
__global__ void prep_wct(const float* __restrict__ Wemb, u16* __restrict__ Wct) {
  int idx = blockIdx.x * 256 + threadIdx.x;
  if (idx >= 3 * C_DIM * D_DIM) return;
  int d = idx & 1023;
  int c = (idx >> 10) & 511;
  int s = idx >> 19;
  Wct[idx] = f2bf(Wemb[(c * D_DIM + d) * 3 + s]);
}

// dst[n][k] bf16 = src[k][n] fp32
__global__ void transpose_w(const float* __restrict__ src, u16* __restrict__ dst, int K, int N) {
  int idx = blockIdx.x * 256 + threadIdx.x;
  if (idx >= K * N) return;
  int k = idx % K, n = idx / K;
  dst[idx] = f2bf(src[(size_t)k * N + n]);
}

__global__ void prep_c1t(const float* __restrict__ c1W, float* __restrict__ Wt) {
  int idx = blockIdx.x * 256 + threadIdx.x;
  if (idx >= C_DIM * 32) return;
  int n = idx & 31;
  int k = idx >> 5;
  Wt[idx] = c1W[n * C_DIM + k];
}

// ---------------- bf16 MFMA GEMM: C[M,N] = epi( sum_s A_s[M,K] @ Bt_s[N,K]^T ) -------
// A row-major bf16 (lda stride), Bt = B^T row-major bf16 [N][K].
// EPI: 0 = store fp32, 1 = C += acc+bias (fp32), 2 = Cbf = bf16(gelu(acc+bias)),
//      3 = C = relu(acc+bias) (fp32)
template <int S, int EPI>
__launch_bounds__(256)
__global__ void gemm_mfma(const u16* __restrict__ A, int lda, int aRowsPerZ,
                          const u16* __restrict__ Bt, size_t bShift, int K,
                          float* __restrict__ C, u16* __restrict__ Cbf,
                          const float* __restrict__ bias, int N, int cRowsPerZ) {
  __shared__ u16 lds[16384];  // A tile 128x64 (8192), B tile 128x64 (8192)
  u16* Alds = lds;
  u16* Blds = lds + 8192;

  const int tid = threadIdx.x;
  const int lane = tid & 63;
  const int wave = tid >> 6;
  const int wm = wave >> 1, wn = wave & 1;
  const int quad = lane >> 4;
  const int l15 = lane & 15;
  const int srow = lane >> 3;          // staging row within 8-row chunk
  const int scol = (lane & 7) * 8;     // staging col (elements)

  const int n0 = blockIdx.x * 128;
  const int arow0 = blockIdx.z * aRowsPerZ + blockIdx.y * 128;
  const int crow0 = blockIdx.z * cRowsPerZ + blockIdx.y * 128;

  f32x4 acc[4][4] = {};

  for (int s = 0; s < S; ++s) {
    const u16* Ab = A + ((size_t)arow0 + s) * (size_t)lda;
    const u16* Bb = Bt + (size_t)s * bShift;
    for (int k0 = 0; k0 < K; k0 += 64) {
#pragma unroll
      for (int c = 0; c < 4; ++c) {
        int chunk = wave * 4 + c;
        gload_lds16(Ab + (size_t)(chunk * 8 + srow) * lda + k0 + scol,
                    Alds + chunk * 512);
      }
#pragma unroll
      for (int c = 0; c < 4; ++c) {
        int chunk = wave * 4 + c;
        gload_lds16(Bb + (size_t)(n0 + chunk * 8 + srow) * K + k0 + scol,
                    Blds + chunk * 512);
      }
      __syncthreads();
#pragma unroll
      for (int kk = 0; kk < 64; kk += 32) {
        bf16x8 af[4], bfr[4];
#pragma unroll
        for (int mt = 0; mt < 4; ++mt)
          af[mt] = *(const bf16x8*)&Alds[(wm * 64 + mt * 16 + l15) * 64 + kk + quad * 8];
#pragma unroll
        for (int nt = 0; nt < 4; ++nt)
          bfr[nt] = *(const bf16x8*)&Blds[(wn * 64 + nt * 16 + l15) * 64 + kk + quad * 8];
#pragma unroll
        for (int mt = 0; mt < 4; ++mt)
#pragma unroll
          for (int nt = 0; nt < 4; ++nt)
            acc[mt][nt] = __builtin_amdgcn_mfma_f32_16x16x32_bf16(af[mt], bfr[nt], acc[mt][nt], 0, 0, 0);
      }
      __syncthreads();
    }
  }

#pragma unroll
  for (int mt = 0; mt < 4; ++mt) {
#pragma unroll
    for (int nt = 0; nt < 4; ++nt) {
      int col = n0 + wn * 64 + nt * 16 + l15;
      float bv = 0.f;
      if constexpr (EPI != 0) bv = bias[col];
#pragma unroll
      for (int r = 0; r < 4; ++r) {
        size_t row = (size_t)crow0 + wm * 64 + mt * 16 + quad * 4 + r;
        float v = acc[mt][nt][r];
        if constexpr (EPI == 0) {
          C[row * N + col] = v;
        } else if constexpr (EPI == 1) {
          C[row * N + col] += v + bv;
        } else if constexpr (EPI == 2) {
          float t = v + bv;
          Cbf[row * N + col] = f2bf(t * 0.5f * (1.f + erff(t * 0.70710678118f)));
        } else {
          C[row * N + col] = fmaxf(v + bv, 0.f);
        }
      }
    }
  }
}

// ---------------- small fp32 GEMM (head c1: N=32) ------------------------------------
template <int NT, int EPI>
__launch_bounds__(256)
__global__ void gemm_f32(const float* __restrict__ A, const float* __restrict__ B,
                         float* __restrict__ C, const float* __restrict__ bias,
                         int M, int N, int K) {
  __shared__ __align__(16) float As[16][68];
  __shared__ __align__(16) float Bs[16][NT + 4];
  int tid = threadIdx.x;
  int tx = tid & 15, ty = tid >> 4;
  int n0 = blockIdx.x * NT, m0 = blockIdx.y * 64;
  constexpr int TN = NT / 16;
  float acc[4][TN] = {};
  int arow = tid >> 2, akg = (tid & 3) * 4;
  int bk, bng;
  if (NT == 64) { bk = tid >> 4; bng = (tid & 15) * 4; }
  else          { bk = tid >> 3; bng = (tid & 7) * 4; }
  bool bload = (NT == 64) || (tid < 128);
  const float* Ap = A + (size_t)(m0 + arow) * K + akg;
  const float* Bp = B + (size_t)bk * N + n0 + bng;
  for (int k0 = 0; k0 < K; k0 += 16) {
    float4 av = *(const float4*)(Ap + k0);
    float4 bv = make_float4(0.f, 0.f, 0.f, 0.f);
    if (bload) bv = *(const float4*)(Bp + (size_t)k0 * N);
    __syncthreads();
    As[akg + 0][arow] = av.x; As[akg + 1][arow] = av.y;
    As[akg + 2][arow] = av.z; As[akg + 3][arow] = av.w;
    if (bload) *(float4*)&Bs[bk][bng] = bv;
    __syncthreads();
#pragma unroll
    for (int k = 0; k < 16; ++k) {
      float4 a4 = *(const float4*)&As[k][ty * 4];
      float a[4] = {a4.x, a4.y, a4.z, a4.w};
      float b[TN];
#pragma unroll
      for (int j = 0; j < TN; j++) b[j] = Bs[k][tx * TN + j];
#pragma unroll
      for (int i = 0; i < 4; i++)
#pragma unroll
        for (int j = 0; j < TN; j++) acc[i][j] = fmaf(a[i], b[j], acc[i][j]);
    }
  }
#pragma unroll
  for (int i = 0; i < 4; i++) {
    size_t row = m0 + ty * 4 + i;
    float* Cp = C + row * (size_t)N + n0 + tx * TN;
#pragma unroll
    for (int j = 0; j < TN; j++) {
      float v = acc[i][j];
      if (EPI >= 1) v += bias[n0 + tx * TN + j];
      Cp[j] = v;
    }
  }
}

// ---------------- LayerNorm over last dim (512), bf16 out ----------------------------
__launch_bounds__(256)
__global__ void ln_kernel(const float* __restrict__ h, const float* __restrict__ g,
                          const float* __restrict__ b, u16* __restrict__ u) {
  int row = blockIdx.x;
  int tid = threadIdx.x;
  const float* hp = h + (size_t)row * C_DIM;
  float v0 = hp[tid], v1 = hp[tid + 256];
  __shared__ float red[4];
  __shared__ float stat[2];
  float s = v0 + v1;
#pragma unroll
  for (int o = 32; o > 0; o >>= 1) s += __shfl_down(s, o);
  if ((tid & 63) == 0) red[tid >> 6] = s;
  __syncthreads();
  if (tid == 0) stat[0] = (red[0] + red[1] + red[2] + red[3]) * (1.f / 512.f);
  __syncthreads();
  float mu = stat[0];
  float d0 = v0 - mu, d1 = v1 - mu;
  float q = d0 * d0 + d1 * d1;
#pragma unroll
  for (int o = 32; o > 0; o >>= 1) q += __shfl_down(q, o);
  if ((tid & 63) == 0) red[tid >> 6] = q;
  __syncthreads();
  if (tid == 0) stat[1] = rsqrtf((red[0] + red[1] + red[2] + red[3]) * (1.f / 512.f) + EPS);
  __syncthreads();
  float rs = stat[1];
  u16* up = u + (size_t)row * C_DIM;
  up[tid] = f2bf(d0 * rs * g[tid] + b[tid]);
  up[tid + 256] = f2bf(d1 * rs * g[tid + 256] + b[tid + 256]);
}

// ---------------- fused attention per (q-tile, head, bn); bf16 out -------------------
__launch_bounds__(256)
__global__ void attn_kernel(const float* __restrict__ qkv, u16* __restrict__ o, int bn_base) {
  __shared__ float Qs[64][132];
  __shared__ float KVs[64][129];
  __shared__ float S[64][260];
  int tid = threadIdx.x;
  int tx = tid & 15, ty = tid >> 4;
  int q0 = blockIdx.x * 64;
  int hh = blockIdx.y;
  int bl = blockIdx.z;
  const float* base = qkv + (size_t)bl * T_SEQ * QKV_N;
#pragma unroll
  for (int it = 0; it < 8; ++it) {
    int idx = tid + it * 256;
    int r = idx >> 5, cg = (idx & 31) * 4;
    float4 v = *(const float4*)(base + (size_t)(q0 + r) * QKV_N + hh * DHEAD + cg);
    Qs[r][cg] = v.x; Qs[r][cg + 1] = v.y; Qs[r][cg + 2] = v.z; Qs[r][cg + 3] = v.w;
  }
  for (int kt = 0; kt < 4; ++kt) {
    __syncthreads();
#pragma unroll
    for (int it = 0; it < 8; ++it) {
      int idx = tid + it * 256;
      int r = idx >> 5, cg = (idx & 31) * 4;
      float4 v = *(const float4*)(base + (size_t)(kt * 64 + r) * QKV_N + C_DIM + hh * DHEAD + cg);
      KVs[r][cg] = v.x; KVs[r][cg + 1] = v.y; KVs[r][cg + 2] = v.z; KVs[r][cg + 3] = v.w;
    }
    __syncthreads();
    float acc[4][4] = {};
#pragma unroll 4
    for (int d = 0; d < DHEAD; ++d) {
      float a[4], b[4];
#pragma unroll
      for (int i = 0; i < 4; i++) a[i] = Qs[ty * 4 + i][d];
#pragma unroll
      for (int j = 0; j < 4; j++) b[j] = KVs[tx * 4 + j][d];
#pragma unroll
      for (int i = 0; i < 4; i++)
#pragma unroll
        for (int j = 0; j < 4; j++) acc[i][j] = fmaf(a[i], b[j], acc[i][j]);
    }
#pragma unroll
    for (int i = 0; i < 4; i++)
#pragma unroll
      for (int j = 0; j < 4; j++)
        S[ty * 4 + i][kt * 64 + tx * 4 + j] = acc[i][j] * ATT_SCALE;
  }
  __syncthreads();
  {
    int r = tid >> 2, p = tid & 3;
    float mx = -1e30f;
#pragma unroll 8
    for (int j = 0; j < 64; j++) mx = fmaxf(mx, S[r][p * 64 + j]);
    mx = fmaxf(mx, __shfl_xor(mx, 1));
    mx = fmaxf(mx, __shfl_xor(mx, 2));
    float sum = 0.f;
#pragma unroll 8
    for (int j = 0; j < 64; j++) {
      float e = expf(S[r][p * 64 + j] - mx);
      S[r][p * 64 + j] = e;
      sum += e;
    }
    sum += __shfl_xor(sum, 1);
    sum += __shfl_xor(sum, 2);
    float inv = 1.f / sum;
#pragma unroll 8
    for (int j = 0; j < 64; j++) S[r][p * 64 + j] *= inv;
  }
  float oacc[4][8] = {};
  for (int kt = 0; kt < 4; ++kt) {
    __syncthreads();
#pragma unroll
    for (int it = 0; it < 8; ++it) {
      int idx = tid + it * 256;
      int r = idx >> 5, cg = (idx & 31) * 4;
      float4 v = *(const float4*)(base + (size_t)(kt * 64 + r) * QKV_N + 2 * C_DIM + hh * DHEAD + cg);
      KVs[r][cg] = v.x; KVs[r][cg + 1] = v.y; KVs[r][cg + 2] = v.z; KVs[r][cg + 3] = v.w;
    }
    __syncthreads();
#pragma unroll 4
    for (int kk = 0; kk < 64; kk++) {
      float p4[4], b[8];
#pragma unroll
      for (int i = 0; i < 4; i++) p4[i] = S[ty * 4 + i][kt * 64 + kk];
#pragma unroll
      for (int j = 0; j < 8; j++) b[j] = KVs[kk][tx * 8 + j];
#pragma unroll
      for (int i = 0; i < 4; i++)
#pragma unroll
        for (int j = 0; j < 8; j++) oacc[i][j] = fmaf(p4[i], b[j], oacc[i][j]);
    }
  }
  int bn = bn_base + bl;
#pragma unroll
  for (int i = 0; i < 4; i++) {
    u16* op = o + ((size_t)bn * T_SEQ + q0 + ty * 4 + i) * C_DIM + hh * DHEAD + tx * 8;
#pragma unroll
    for (int j = 0; j < 8; j++) op[j] = f2bf(oacc[i][j]);
  }
}

// ---------------- NormalHead ---------------------------------------------------------
__global__ void head_kernel(const float* __restrict__ x1,
                            const float* __restrict__ bn1g, const float* __restrict__ bn1b,
                            const float* __restrict__ bn1rm, const float* __restrict__ bn1rv,
                            const float* __restrict__ c2W, const float* __restrict__ c2b,
                            const float* __restrict__ bn2g, const float* __restrict__ bn2b,
                            const float* __restrict__ bn2rm, const float* __restrict__ bn2rv,
                            const float* __restrict__ c3W, const float* __restrict__ c3b,
                            float* __restrict__ d1a, float* __restrict__ d2a, float* __restrict__ sca) {
  int r = blockIdx.x * 256 + threadIdx.x;
  if (r >= BN_TOT * T_SEQ) return;
  const float* xp = x1 + (size_t)r * 32;
  float y[32];
  float d1 = 0.f;
#pragma unroll
  for (int oc = 0; oc < 32; oc++) {
    float v = xp[oc];
    float dm = v - bn1rm[oc];
    d1 += dm * dm / bn1rv[oc];
    float t = dm * rsqrtf(bn1rv[oc] + EPS) * bn1g[oc] + bn1b[oc];
    y[oc] = fmaxf(t, 0.f);
  }
  float d2 = 0.f, sacc = 0.f;
#pragma unroll
  for (int o2 = 0; o2 < 16; o2++) {
    float s2 = 0.f;
#pragma unroll
    for (int oc = 0; oc < 32; oc++) s2 = fmaf(y[oc], c2W[o2 * 32 + oc], s2);
    s2 += c2b[o2];
    float dm = s2 - bn2rm[o2];
    d2 += dm * dm / bn2rv[o2];
    float t = dm * rsqrtf(bn2rv[o2] + EPS) * bn2g[o2] + bn2b[o2];
    t = fmaxf(t, 0.f);
    sacc = fmaf(t, c3W[o2], sacc);
  }
  float sc = 1.f / (1.f + expf(-(sacc + c3b[0])));
  d1a[r] = sqrtf(d1);
  d2a[r] = sqrtf(d2);
  sca[r] = sc;
}

__global__ void reduce_kernel(const float* __restrict__ d1a, const float* __restrict__ d2a,
                              const float* __restrict__ sca, float* __restrict__ out) {
  int idx = blockIdx.x * 256 + threadIdx.x;
  if (idx >= 32 * T_SEQ) return;
  int b = idx >> 8, t = idx & 255;
  float s1 = 0.f, s2 = 0.f, ss = 0.f;
  for (int n = 0; n < 10; n++) {
    int r = (b * 10 + n) * T_SEQ + t;
    s1 += d1a[r];
    s2 += d2a[r];
    ss += sca[r];
  }
  out[idx] = (s1 + s2) * ss * 0.01f;
}

extern "C" void kernel_launch(void* const* d_in, const int* in_sizes, int n_in,
                              void* d_out, int out_size, void* d_ws, size_t ws_size,
                              hipStream_t stream) {
  const float* x     = (const float*)d_in[0];
  const float* Wemb  = (const float*)d_in[1];
  const float* bemb  = (const float*)d_in[2];
  const float* ln1g  = (const float*)d_in[3];
  const float* ln1b  = (const float*)d_in[4];
  const float* Wqkv  = (const float*)d_in[5];
  const float* Wo    = (const float*)d_in[6];
  const float* bo    = (const float*)d_in[7];
  const float* ln2g  = (const float*)d_in[8];
  const float* ln2b  = (const float*)d_in[9];
  const float* W1    = (const float*)d_in[10];
  const float* b1    = (const float*)d_in[11];
  const float* W2    = (const float*)d_in[12];
  const float* b2    = (const float*)d_in[13];
  const float* c1W   = (const float*)d_in[14];
  const float* c1b   = (const float*)d_in[15];
  const float* bn1g  = (const float*)d_in[16];
  const float* bn1b  = (const float*)d_in[17];
  const float* bn1rm = (const float*)d_in[18];
  const float* bn1rv = (const float*)d_in[19];
  const float* c2W   = (const float*)d_in[20];
  const float* c2b   = (const float*)d_in[21];
  const float* bn2g  = (const float*)d_in[22];
  const float* bn2b  = (const float*)d_in[23];
  const float* bn2rm = (const float*)d_in[24];
  const float* bn2rv = (const float*)d_in[25];
  const float* c3W   = (const float*)d_in[26];
  const float* c3b   = (const float*)d_in[27];

  char* w = (char*)d_ws;
  size_t off = 0;
  auto alloc = [&](size_t nbytes) {
    void* p = (void*)(w + off);
    off += (nbytes + 255) & ~(size_t)255;
    return p;
  };
  float* h     = (float*)alloc((size_t)BN_TOT * T_SEQ * C_DIM * 4);   // 168 MB
  u16*   u_bf  = (u16*)  alloc((size_t)BN_TOT * T_SEQ * C_DIM * 2);   // 84 MB
  float* qkvb  = (float*)alloc((size_t)80 * T_SEQ * QKV_N * 4);       // 126 MB (also mlp-mid bf16)
  u16*   xpad  = (u16*)  alloc((size_t)BN_TOT * 258 * 1024 * 2);      // 169 MB
  u16*   Wct   = (u16*)  alloc((size_t)3 * C_DIM * D_DIM * 2);
  u16*   Wqkvt = (u16*)  alloc((size_t)2 * QKV_N * C_DIM * 2);
  u16*   Wot   = (u16*)  alloc((size_t)2 * C_DIM * C_DIM * 2);
  u16*   W1t   = (u16*)  alloc((size_t)2 * C_DIM * C_DIM * 2);
  u16*   W2t   = (u16*)  alloc((size_t)2 * C_DIM * C_DIM * 2);
  float* Wc1t  = (float*)alloc((size_t)C_DIM * 32 * 4);
  float* x1    = (float*)alloc((size_t)BN_TOT * T_SEQ * 32 * 4);
  float* d1a   = (float*)alloc((size_t)BN_TOT * T_SEQ * 4);
  float* d2a   = (float*)alloc((size_t)BN_TOT * T_SEQ * 4);
  float* sca   = (float*)alloc((size_t)BN_TOT * T_SEQ * 4);
  u16*   midbf = (u16*)qkvb;  // reuse qkvb space for mlp mid (84 MB <= 126 MB)

  // ---- prep: bf16 conversions + weight transposes ----
  {
    size_t nx = (size_t)BN_TOT * 258 * 1024;
    convert_x<<<(unsigned)((nx + 255) / 256), 256, 0, stream>>>(x, xpad);
  }
  prep_wct<<<(3 * C_DIM * D_DIM + 255) / 256, 256, 0, stream>>>(Wemb, Wct);
  for (int l = 0; l < 2; ++l) {
    transpose_w<<<(C_DIM * QKV_N + 255) / 256, 256, 0, stream>>>(
        Wqkv + (size_t)l * C_DIM * QKV_N, Wqkvt + (size_t)l * QKV_N * C_DIM, C_DIM, QKV_N);
    transpose_w<<<(C_DIM * C_DIM + 255) / 256, 256, 0, stream>>>(
        Wo + (size_t)l * C_DIM * C_DIM, Wot + (size_t)l * C_DIM * C_DIM, C_DIM, C_DIM);
    transpose_w<<<(C_DIM * C_DIM + 255) / 256, 256, 0, stream>>>(
        W1 + (size_t)l * C_DIM * C_DIM, W1t + (size_t)l * C_DIM * C_DIM, C_DIM, C_DIM);
    transpose_w<<<(C_DIM * C_DIM + 255) / 256, 256, 0, stream>>>(
        W2 + (size_t)l * C_DIM * C_DIM, W2t + (size_t)l * C_DIM * C_DIM, C_DIM, C_DIM);
  }
  prep_c1t<<<(C_DIM * 32 + 255) / 256, 256, 0, stream>>>(c1W, Wc1t);

  // ---- conv: 3 shifted GEMM passes over padded bf16 x; relu+bias -> h fp32 ----
  gemm_mfma<3, 3><<<dim3(C_DIM / 128, 2, BN_TOT), 256, 0, stream>>>(
      xpad, 1024, 258, Wct, (size_t)C_DIM * D_DIM, D_DIM, h, nullptr, bemb, C_DIM, 256);

  for (int l = 0; l < 2; ++l) {
    ln_kernel<<<BN_TOT * T_SEQ, 256, 0, stream>>>(h, ln1g + l * C_DIM, ln1b + l * C_DIM, u_bf);
    for (int c = 0; c < 4; ++c) {
      gemm_mfma<1, 0><<<dim3(QKV_N / 128, 160, 1), 256, 0, stream>>>(
          u_bf + (size_t)c * 20480 * C_DIM, C_DIM, 0,
          Wqkvt + (size_t)l * QKV_N * C_DIM, 0, C_DIM, qkvb, nullptr, nullptr, QKV_N, 0);
      attn_kernel<<<dim3(4, NHEAD, 80), 256, 0, stream>>>(qkvb, u_bf, c * 80);
    }
    gemm_mfma<1, 1><<<dim3(C_DIM / 128, 640, 1), 256, 0, stream>>>(
        u_bf, C_DIM, 0, Wot + (size_t)l * C_DIM * C_DIM, 0, C_DIM, h, nullptr, bo + l * C_DIM, C_DIM, 0);
    ln_kernel<<<BN_TOT * T_SEQ, 256, 0, stream>>>(h, ln2g + l * C_DIM, ln2b + l * C_DIM, u_bf);
    gemm_mfma<1, 2><<<dim3(C_DIM / 128, 640, 1), 256, 0, stream>>>(
        u_bf, C_DIM, 0, W1t + (size_t)l * C_DIM * C_DIM, 0, C_DIM, nullptr, midbf, b1 + l * C_DIM, C_DIM, 0);
    gemm_mfma<1, 1><<<dim3(C_DIM / 128, 640, 1), 256, 0, stream>>>(
        midbf, C_DIM, 0, W2t + (size_t)l * C_DIM * C_DIM, 0, C_DIM, h, nullptr, b2 + l * C_DIM, C_DIM, 0);
  }

  gemm_f32<32, 1><<<dim3(1, 81920 / 64), 256, 0, stream>>>(h, Wc1t, x1, c1b, 81920, 32, C_DIM);
  head_kernel<<<(BN_TOT * T_SEQ + 255) / 256, 256, 0, stream>>>(
      x1, bn1g, bn1b, bn1rm, bn1rv, c2W, c2b, bn2g, bn2b, bn2rm, bn2rv, c3W, c3b, d1a, d2a, sca);
  reduce_kernel<<<32, 256, 0, stream>>>(d1a, d2a, sca, (float*)d_out);
}

// Round 3
// 3121.077 us; speedup vs baseline: 4.3635x; 1.7703x over previous
//
#include <hip/hip_runtime.h>
#include <math.h>

#define T_SEQ 256
#define C_DIM 512
#define D_DIM 1024
#define BN_TOT 320
#define NHEAD 4
#define DHEAD 128
#define QKV_N 1536
#define EPS 1e-5f
#define ATT_SCALE 0.08838834764831845f

typedef unsigned short u16;
typedef unsigned int u32;
typedef __attribute__((ext_vector_type(8))) short bf16x8;
typedef __attribute__((ext_vector_type(4))) float f32x4;

__device__ __forceinline__ u16 f2bf(float f) {
  union { float f; u32 u; } v; v.f = f;
  u32 r = v.u + 0x7fffu + ((v.u >> 16) & 1u);
  return (u16)(r >> 16);
}

__device__ __forceinline__ void gload_lds16(const u16* g, u16* l) {
  __builtin_amdgcn_global_load_lds((const __attribute__((address_space(1))) u32*)g,
                                   (__attribute__((address_space(3))) u32*)l, 16, 0, 0);
}

// ---------------- prep kernels -------------------------------------------------------
__global__ void convert_x(const float* __restrict__ x, u16* __restrict__ xpad) {
  size_t idx = (size_t)blockIdx.x * 256 + threadIdx.x;
  if (idx >= (size_t)BN_TOT * 258 * 1024) return;
  size_t row = idx >> 10; int col = idx & 1023;
  int bn = (int)(row / 258), tr = (int)(row % 258);
  float v = (tr == 0 || tr == 257) ? 0.f : x[((size_t)bn * 256 + tr - 1) * 1024 + col];
  xpad[idx] = f2bf(v);
}

__global__ void prep_wct(const float* __restrict__ Wemb, u16* __restrict__ Wct) {
  int idx = blockIdx.x * 256 + threadIdx.x;
  if (idx >= 3 * C_DIM * D_DIM) return;
  int d = idx & 1023;
  int c = (idx >> 10) & 511;
  int s = idx >> 19;
  Wct[idx] = f2bf(Wemb[(c * D_DIM + d) * 3 + s]);
}

__global__ void transpose_w(const float* __restrict__ src, u16* __restrict__ dst, int K, int N) {
  int idx = blockIdx.x * 256 + threadIdx.x;
  if (idx >= K * N) return;
  int k = idx % K, n = idx / K;
  dst[idx] = f2bf(src[(size_t)k * N + n]);
}

__global__ void prep_c1t(const float* __restrict__ c1W, float* __restrict__ Wt) {
  int idx = blockIdx.x * 256 + threadIdx.x;
  if (idx >= C_DIM * 32) return;
  int n = idx & 31;
  int k = idx >> 5;
  Wt[idx] = c1W[n * C_DIM + k];
}

// ---------------- bf16 MFMA GEMM -----------------------------------------------------
// EPI: 0 = store fp32, 1 = C += acc+bias (fp32), 2 = Cbf = bf16(gelu(acc+bias)),
//      3 = C = relu(acc+bias) fp32, 4 = Cbf = bf16(acc)
template <int S, int EPI>
__launch_bounds__(256)
__global__ void gemm_mfma(const u16* __restrict__ A, int lda, int aRowsPerZ,
                          const u16* __restrict__ Bt, size_t bShift, int K,
                          float* __restrict__ C, u16* __restrict__ Cbf,
                          const float* __restrict__ bias, int N, int cRowsPerZ) {
  __shared__ u16 lds[16384];
  u16* Alds = lds;
  u16* Blds = lds + 8192;

  const int tid = threadIdx.x;
  const int lane = tid & 63;
  const int wave = tid >> 6;
  const int wm = wave >> 1, wn = wave & 1;
  const int quad = lane >> 4;
  const int l15 = lane & 15;
  const int srow = lane >> 3;
  const int scol = (lane & 7) * 8;

  const int n0 = blockIdx.x * 128;
  const int arow0 = blockIdx.z * aRowsPerZ + blockIdx.y * 128;
  const int crow0 = blockIdx.z * cRowsPerZ + blockIdx.y * 128;

  f32x4 acc[4][4] = {};

  for (int s = 0; s < S; ++s) {
    const u16* Ab = A + ((size_t)arow0 + s) * (size_t)lda;
    const u16* Bb = Bt + (size_t)s * bShift;
    for (int k0 = 0; k0 < K; k0 += 64) {
#pragma unroll
      for (int c = 0; c < 4; ++c) {
        int chunk = wave * 4 + c;
        gload_lds16(Ab + (size_t)(chunk * 8 + srow) * lda + k0 + scol,
                    Alds + chunk * 512);
      }
#pragma unroll
      for (int c = 0; c < 4; ++c) {
        int chunk = wave * 4 + c;
        gload_lds16(Bb + (size_t)(n0 + chunk * 8 + srow) * K + k0 + scol,
                    Blds + chunk * 512);
      }
      __syncthreads();
#pragma unroll
      for (int kk = 0; kk < 64; kk += 32) {
        bf16x8 af[4], bfr[4];
#pragma unroll
        for (int mt = 0; mt < 4; ++mt)
          af[mt] = *(const bf16x8*)&Alds[(wm * 64 + mt * 16 + l15) * 64 + kk + quad * 8];
#pragma unroll
        for (int nt = 0; nt < 4; ++nt)
          bfr[nt] = *(const bf16x8*)&Blds[(wn * 64 + nt * 16 + l15) * 64 + kk + quad * 8];
#pragma unroll
        for (int mt = 0; mt < 4; ++mt)
#pragma unroll
          for (int nt = 0; nt < 4; ++nt)
            acc[mt][nt] = __builtin_amdgcn_mfma_f32_16x16x32_bf16(af[mt], bfr[nt], acc[mt][nt], 0, 0, 0);
      }
      __syncthreads();
    }
  }

#pragma unroll
  for (int mt = 0; mt < 4; ++mt) {
#pragma unroll
    for (int nt = 0; nt < 4; ++nt) {
      int col = n0 + wn * 64 + nt * 16 + l15;
      float bv = 0.f;
      if constexpr (EPI == 1 || EPI == 2 || EPI == 3) bv = bias[col];
#pragma unroll
      for (int r = 0; r < 4; ++r) {
        size_t row = (size_t)crow0 + wm * 64 + mt * 16 + quad * 4 + r;
        float v = acc[mt][nt][r];
        if constexpr (EPI == 0) {
          C[row * N + col] = v;
        } else if constexpr (EPI == 1) {
          C[row * N + col] += v + bv;
        } else if constexpr (EPI == 2) {
          float t = v + bv;
          Cbf[row * N + col] = f2bf(t * 0.5f * (1.f + erff(t * 0.70710678118f)));
        } else if constexpr (EPI == 3) {
          C[row * N + col] = fmaxf(v + bv, 0.f);
        } else {
          Cbf[row * N + col] = f2bf(v);
        }
      }
    }
  }
}

// ---------------- small fp32 GEMM (head c1: N=32) ------------------------------------
template <int NT, int EPI>
__launch_bounds__(256)
__global__ void gemm_f32(const float* __restrict__ A, const float* __restrict__ B,
                         float* __restrict__ C, const float* __restrict__ bias,
                         int M, int N, int K) {
  __shared__ __align__(16) float As[16][68];
  __shared__ __align__(16) float Bs[16][NT + 4];
  int tid = threadIdx.x;
  int tx = tid & 15, ty = tid >> 4;
  int n0 = blockIdx.x * NT, m0 = blockIdx.y * 64;
  constexpr int TN = NT / 16;
  float acc[4][TN] = {};
  int arow = tid >> 2, akg = (tid & 3) * 4;
  int bk, bng;
  if (NT == 64) { bk = tid >> 4; bng = (tid & 15) * 4; }
  else          { bk = tid >> 3; bng = (tid & 7) * 4; }
  bool bload = (NT == 64) || (tid < 128);
  const float* Ap = A + (size_t)(m0 + arow) * K + akg;
  const float* Bp = B + (size_t)bk * N + n0 + bng;
  for (int k0 = 0; k0 < K; k0 += 16) {
    float4 av = *(const float4*)(Ap + k0);
    float4 bv = make_float4(0.f, 0.f, 0.f, 0.f);
    if (bload) bv = *(const float4*)(Bp + (size_t)k0 * N);
    __syncthreads();
    As[akg + 0][arow] = av.x; As[akg + 1][arow] = av.y;
    As[akg + 2][arow] = av.z; As[akg + 3][arow] = av.w;
    if (bload) *(float4*)&Bs[bk][bng] = bv;
    __syncthreads();
#pragma unroll
    for (int k = 0; k < 16; ++k) {
      float4 a4 = *(const float4*)&As[k][ty * 4];
      float a[4] = {a4.x, a4.y, a4.z, a4.w};
      float b[TN];
#pragma unroll
      for (int j = 0; j < TN; j++) b[j] = Bs[k][tx * TN + j];
#pragma unroll
      for (int i = 0; i < 4; i++)
#pragma unroll
        for (int j = 0; j < TN; j++) acc[i][j] = fmaf(a[i], b[j], acc[i][j]);
    }
  }
#pragma unroll
  for (int i = 0; i < 4; i++) {
    size_t row = m0 + ty * 4 + i;
    float* Cp = C + row * (size_t)N + n0 + tx * TN;
#pragma unroll
    for (int j = 0; j < TN; j++) {
      float v = acc[i][j];
      if (EPI >= 1) v += bias[n0 + tx * TN + j];
      Cp[j] = v;
    }
  }
}

// ---------------- LayerNorm over last dim (512), bf16 out ----------------------------
__launch_bounds__(256)
__global__ void ln_kernel(const float* __restrict__ h, const float* __restrict__ g,
                          const float* __restrict__ b, u16* __restrict__ u) {
  int row = blockIdx.x;
  int tid = threadIdx.x;
  const float* hp = h + (size_t)row * C_DIM;
  float v0 = hp[tid], v1 = hp[tid + 256];
  __shared__ float red[4];
  __shared__ float stat[2];
  float s = v0 + v1;
#pragma unroll
  for (int o = 32; o > 0; o >>= 1) s += __shfl_down(s, o);
  if ((tid & 63) == 0) red[tid >> 6] = s;
  __syncthreads();
  if (tid == 0) stat[0] = (red[0] + red[1] + red[2] + red[3]) * (1.f / 512.f);
  __syncthreads();
  float mu = stat[0];
  float d0 = v0 - mu, d1 = v1 - mu;
  float q = d0 * d0 + d1 * d1;
#pragma unroll
  for (int o = 32; o > 0; o >>= 1) q += __shfl_down(q, o);
  if ((tid & 63) == 0) red[tid >> 6] = q;
  __syncthreads();
  if (tid == 0) stat[1] = rsqrtf((red[0] + red[1] + red[2] + red[3]) * (1.f / 512.f) + EPS);
  __syncthreads();
  float rs = stat[1];
  u16* up = u + (size_t)row * C_DIM;
  up[tid] = f2bf(d0 * rs * g[tid] + b[tid]);
  up[tid + 256] = f2bf(d1 * rs * g[tid + 256] + b[tid + 256]);
}

// ---------------- MFMA flash attention: block = (head, bn), 8 waves ------------------
// qkv bf16 [bn][t][1536]; out bf16 [bn][t][512] at col hh*128.
__launch_bounds__(512, 2)
__global__ void attn_mfma(const u16* __restrict__ qkv, u16* __restrict__ o) {
  __shared__ u16 Ks[64 * 136];        // [kk][d], pad 136
  __shared__ u32 Vt32[128 * 44];      // [d][kk-pair], pad 44 dwords (=88 u16)
  __shared__ u16 Ps[8][32 * 80];      // per-wave P [m][kk], pad 80

  const int tid = threadIdx.x;
  const int lane = tid & 63, wave = tid >> 6;
  const int quad = lane >> 4, l15 = lane & 15;
  const int hh = blockIdx.x, bl = blockIdx.y;
  const u16* base = qkv + (size_t)bl * T_SEQ * QKV_N;

  // Q fragments in registers: rows wave*32 + mi*16 + l15
  bf16x8 qf[2][4];
#pragma unroll
  for (int mi = 0; mi < 2; mi++) {
    int row = wave * 32 + mi * 16 + l15;
    const u16* qp = base + (size_t)row * QKV_N + hh * DHEAD + quad * 8;
#pragma unroll
    for (int k0 = 0; k0 < 4; k0++)
      qf[mi][k0] = *(const bf16x8*)(qp + k0 * 32);
  }

  f32x4 oa[2][8] = {};
  float mrow[2][4], lrow[2][4];
#pragma unroll
  for (int mi = 0; mi < 2; mi++)
#pragma unroll
    for (int r = 0; r < 4; r++) { mrow[mi][r] = -1e30f; lrow[mi][r] = 0.f; }

  for (int kt = 0; kt < 4; kt++) {
    __syncthreads();
    // K tile 64x128 -> Ks (16 elems / thread)
    {
      int kk = tid >> 3, dbase = (tid & 7) * 16;
      const u16* kp = base + (size_t)(kt * 64 + kk) * QKV_N + C_DIM + hh * DHEAD + dbase;
      uint4 a = *(const uint4*)kp;
      uint4 b = *(const uint4*)(kp + 8);
      *(uint4*)&Ks[kk * 136 + dbase] = a;
      *(uint4*)&Ks[kk * 136 + dbase + 8] = b;
    }
    // V tile 64x128 -> Vt32 transposed (pairs of kk packed in u32)
    {
      int kkp = tid >> 4, dbase = (tid & 15) * 8;
      const u16* vp = base + (size_t)(kt * 64 + kkp * 2) * QKV_N + 2 * C_DIM + hh * DHEAD + dbase;
      union { uint4 u; u16 h[8]; } va, vb;
      va.u = *(const uint4*)vp;
      vb.u = *(const uint4*)(vp + QKV_N);
#pragma unroll
      for (int j = 0; j < 8; j++)
        Vt32[(dbase + j) * 44 + kkp] = (u32)va.h[j] | ((u32)vb.h[j] << 16);
    }
    __syncthreads();

    // S = Q @ K^T (raw, scaled later)
    f32x4 sa[2][4] = {};
#pragma unroll
    for (int k0 = 0; k0 < 4; k0++) {
      bf16x8 kf[4];
#pragma unroll
      for (int ni = 0; ni < 4; ni++)
        kf[ni] = *(const bf16x8*)&Ks[(ni * 16 + l15) * 136 + k0 * 32 + quad * 8];
#pragma unroll
      for (int mi = 0; mi < 2; mi++)
#pragma unroll
        for (int ni = 0; ni < 4; ni++)
          sa[mi][ni] = __builtin_amdgcn_mfma_f32_16x16x32_bf16(qf[mi][k0], kf[ni], sa[mi][ni], 0, 0, 0);
    }

    // online softmax (rows = quad*4+r within 16-tile; 16 lanes l15 share a row)
#pragma unroll
    for (int mi = 0; mi < 2; mi++) {
#pragma unroll
      for (int r = 0; r < 4; r++) {
        float mx = fmaxf(fmaxf(sa[mi][0][r], sa[mi][1][r]), fmaxf(sa[mi][2][r], sa[mi][3][r]));
        mx = fmaxf(mx, __shfl_xor(mx, 1));
        mx = fmaxf(mx, __shfl_xor(mx, 2));
        mx = fmaxf(mx, __shfl_xor(mx, 4));
        mx = fmaxf(mx, __shfl_xor(mx, 8));
        mx *= ATT_SCALE;
        float mnew = fmaxf(mrow[mi][r], mx);
        float alpha = __expf(mrow[mi][r] - mnew);
        mrow[mi][r] = mnew;
        float rs = 0.f;
#pragma unroll
        for (int ni = 0; ni < 4; ni++) {
          float p = __expf(sa[mi][ni][r] * ATT_SCALE - mnew);
          rs += p;
          Ps[wave][(mi * 16 + quad * 4 + r) * 80 + ni * 16 + l15] = f2bf(p);
        }
        rs += __shfl_xor(rs, 1);
        rs += __shfl_xor(rs, 2);
        rs += __shfl_xor(rs, 4);
        rs += __shfl_xor(rs, 8);
        lrow[mi][r] = lrow[mi][r] * alpha + rs;
#pragma unroll
        for (int nj = 0; nj < 8; nj++) oa[mi][nj][r] *= alpha;
      }
    }

    // O += P @ V
#pragma unroll
    for (int k0 = 0; k0 < 2; k0++) {
      bf16x8 pf[2];
#pragma unroll
      for (int mi = 0; mi < 2; mi++)
        pf[mi] = *(const bf16x8*)&Ps[wave][(mi * 16 + l15) * 80 + k0 * 32 + quad * 8];
#pragma unroll
      for (int nj = 0; nj < 8; nj++) {
        bf16x8 vf = *(const bf16x8*)&Vt32[(nj * 16 + l15) * 44 + k0 * 16 + quad * 4];
#pragma unroll
        for (int mi = 0; mi < 2; mi++)
          oa[mi][nj] = __builtin_amdgcn_mfma_f32_16x16x32_bf16(pf[mi], vf, oa[mi][nj], 0, 0, 0);
      }
    }
  }

  // epilogue: normalize and store bf16
#pragma unroll
  for (int mi = 0; mi < 2; mi++) {
#pragma unroll
    for (int r = 0; r < 4; r++) {
      int row = wave * 32 + mi * 16 + quad * 4 + r;
      float inv = 1.f / lrow[mi][r];
      u16* op = o + ((size_t)bl * T_SEQ + row) * C_DIM + hh * DHEAD + l15;
#pragma unroll
      for (int nj = 0; nj < 8; nj++)
        op[nj * 16] = f2bf(oa[mi][nj][r] * inv);
    }
  }
}

// ---------------- NormalHead ---------------------------------------------------------
__global__ void head_kernel(const float* __restrict__ x1,
                            const float* __restrict__ bn1g, const float* __restrict__ bn1b,
                            const float* __restrict__ bn1rm, const float* __restrict__ bn1rv,
                            const float* __restrict__ c2W, const float* __restrict__ c2b,
                            const float* __restrict__ bn2g, const float* __restrict__ bn2b,
                            const float* __restrict__ bn2rm, const float* __restrict__ bn2rv,
                            const float* __restrict__ c3W, const float* __restrict__ c3b,
                            float* __restrict__ d1a, float* __restrict__ d2a, float* __restrict__ sca) {
  int r = blockIdx.x * 256 + threadIdx.x;
  if (r >= BN_TOT * T_SEQ) return;
  const float* xp = x1 + (size_t)r * 32;
  float y[32];
  float d1 = 0.f;
#pragma unroll
  for (int oc = 0; oc < 32; oc++) {
    float v = xp[oc];
    float dm = v - bn1rm[oc];
    d1 += dm * dm / bn1rv[oc];
    float t = dm * rsqrtf(bn1rv[oc] + EPS) * bn1g[oc] + bn1b[oc];
    y[oc] = fmaxf(t, 0.f);
  }
  float d2 = 0.f, sacc = 0.f;
#pragma unroll
  for (int o2 = 0; o2 < 16; o2++) {
    float s2 = 0.f;
#pragma unroll
    for (int oc = 0; oc < 32; oc++) s2 = fmaf(y[oc], c2W[o2 * 32 + oc], s2);
    s2 += c2b[o2];
    float dm = s2 - bn2rm[o2];
    d2 += dm * dm / bn2rv[o2];
    float t = dm * rsqrtf(bn2rv[o2] + EPS) * bn2g[o2] + bn2b[o2];
    t = fmaxf(t, 0.f);
    sacc = fmaf(t, c3W[o2], sacc);
  }
  float sc = 1.f / (1.f + expf(-(sacc + c3b[0])));
  d1a[r] = sqrtf(d1);
  d2a[r] = sqrtf(d2);
  sca[r] = sc;
}

__global__ void reduce_kernel(const float* __restrict__ d1a, const float* __restrict__ d2a,
                              const float* __restrict__ sca, float* __restrict__ out) {
  int idx = blockIdx.x * 256 + threadIdx.x;
  if (idx >= 32 * T_SEQ) return;
  int b = idx >> 8, t = idx & 255;
  float s1 = 0.f, s2 = 0.f, ss = 0.f;
  for (int n = 0; n < 10; n++) {
    int r = (b * 10 + n) * T_SEQ + t;
    s1 += d1a[r];
    s2 += d2a[r];
    ss += sca[r];
  }
  out[idx] = (s1 + s2) * ss * 0.01f;
}

extern "C" void kernel_launch(void* const* d_in, const int* in_sizes, int n_in,
                              void* d_out, int out_size, void* d_ws, size_t ws_size,
                              hipStream_t stream) {
  const float* x     = (const float*)d_in[0];
  const float* Wemb  = (const float*)d_in[1];
  const float* bemb  = (const float*)d_in[2];
  const float* ln1g  = (const float*)d_in[3];
  const float* ln1b  = (const float*)d_in[4];
  const float* Wqkv  = (const float*)d_in[5];
  const float* Wo    = (const float*)d_in[6];
  const float* bo    = (const float*)d_in[7];
  const float* ln2g  = (const float*)d_in[8];
  const float* ln2b  = (const float*)d_in[9];
  const float* W1    = (const float*)d_in[10];
  const float* b1    = (const float*)d_in[11];
  const float* W2    = (const float*)d_in[12];
  const float* b2    = (const float*)d_in[13];
  const float* c1W   = (const float*)d_in[14];
  const float* c1b   = (const float*)d_in[15];
  const float* bn1g  = (const float*)d_in[16];
  const float* bn1b  = (const float*)d_in[17];
  const float* bn1rm = (const float*)d_in[18];
  const float* bn1rv = (const float*)d_in[19];
  const float* c2W   = (const float*)d_in[20];
  const float* c2b   = (const float*)d_in[21];
  const float* bn2g  = (const float*)d_in[22];
  const float* bn2b  = (const float*)d_in[23];
  const float* bn2rm = (const float*)d_in[24];
  const float* bn2rv = (const float*)d_in[25];
  const float* c3W   = (const float*)d_in[26];
  const float* c3b   = (const float*)d_in[27];

  char* w = (char*)d_ws;
  size_t off = 0;
  auto alloc = [&](size_t nbytes) {
    void* p = (void*)(w + off);
    off += (nbytes + 255) & ~(size_t)255;
    return p;
  };
  float* h      = (float*)alloc((size_t)BN_TOT * T_SEQ * C_DIM * 4);   // 168 MB
  u16*   u_bf   = (u16*)  alloc((size_t)BN_TOT * T_SEQ * C_DIM * 2);   // 84 MB
  u16*   scratch= (u16*)  alloc((size_t)BN_TOT * T_SEQ * QKV_N * 2);   // 252 MB: xpad / qkv / mlp-mid
  u16*   Wct    = (u16*)  alloc((size_t)3 * C_DIM * D_DIM * 2);
  u16*   Wqkvt  = (u16*)  alloc((size_t)2 * QKV_N * C_DIM * 2);
  u16*   Wot    = (u16*)  alloc((size_t)2 * C_DIM * C_DIM * 2);
  u16*   W1t    = (u16*)  alloc((size_t)2 * C_DIM * C_DIM * 2);
  u16*   W2t    = (u16*)  alloc((size_t)2 * C_DIM * C_DIM * 2);
  float* Wc1t   = (float*)alloc((size_t)C_DIM * 32 * 4);
  float* x1     = (float*)alloc((size_t)BN_TOT * T_SEQ * 32 * 4);
  float* d1a    = (float*)alloc((size_t)BN_TOT * T_SEQ * 4);
  float* d2a    = (float*)alloc((size_t)BN_TOT * T_SEQ * 4);
  float* sca    = (float*)alloc((size_t)BN_TOT * T_SEQ * 4);
  u16* xpad  = scratch;   // 169 MB, dead after conv
  u16* qkvbf = scratch;   // 252 MB, per layer
  u16* midbf = scratch;   // 84 MB mlp mid (qkv dead by then)

  {
    size_t nx = (size_t)BN_TOT * 258 * 1024;
    convert_x<<<(unsigned)((nx + 255) / 256), 256, 0, stream>>>(x, xpad);
  }
  prep_wct<<<(3 * C_DIM * D_DIM + 255) / 256, 256, 0, stream>>>(Wemb, Wct);
  for (int l = 0; l < 2; ++l) {
    transpose_w<<<(C_DIM * QKV_N + 255) / 256, 256, 0, stream>>>(
        Wqkv + (size_t)l * C_DIM * QKV_N, Wqkvt + (size_t)l * QKV_N * C_DIM, C_DIM, QKV_N);
    transpose_w<<<(C_DIM * C_DIM + 255) / 256, 256, 0, stream>>>(
        Wo + (size_t)l * C_DIM * C_DIM, Wot + (size_t)l * C_DIM * C_DIM, C_DIM, C_DIM);
    transpose_w<<<(C_DIM * C_DIM + 255) / 256, 256, 0, stream>>>(
        W1 + (size_t)l * C_DIM * C_DIM, W1t + (size_t)l * C_DIM * C_DIM, C_DIM, C_DIM);
    transpose_w<<<(C_DIM * C_DIM + 255) / 256, 256, 0, stream>>>(
        W2 + (size_t)l * C_DIM * C_DIM, W2t + (size_t)l * C_DIM * C_DIM, C_DIM, C_DIM);
  }
  prep_c1t<<<(C_DIM * 32 + 255) / 256, 256, 0, stream>>>(c1W, Wc1t);

  // conv as 3 shifted GEMMs over padded bf16 x, relu+bias -> h fp32
  gemm_mfma<3, 3><<<dim3(C_DIM / 128, 2, BN_TOT), 256, 0, stream>>>(
      xpad, 1024, 258, Wct, (size_t)C_DIM * D_DIM, D_DIM, h, nullptr, bemb, C_DIM, 256);

  for (int l = 0; l < 2; ++l) {
    ln_kernel<<<BN_TOT * T_SEQ, 256, 0, stream>>>(h, ln1g + l * C_DIM, ln1b + l * C_DIM, u_bf);
    gemm_mfma<1, 4><<<dim3(QKV_N / 128, 640, 1), 256, 0, stream>>>(
        u_bf, C_DIM, 0, Wqkvt + (size_t)l * QKV_N * C_DIM, 0, C_DIM,
        nullptr, qkvbf, nullptr, QKV_N, 0);
    attn_mfma<<<dim3(NHEAD, BN_TOT), 512, 0, stream>>>(qkvbf, u_bf);
    gemm_mfma<1, 1><<<dim3(C_DIM / 128, 640, 1), 256, 0, stream>>>(
        u_bf, C_DIM, 0, Wot + (size_t)l * C_DIM * C_DIM, 0, C_DIM, h, nullptr, bo + l * C_DIM, C_DIM, 0);
    ln_kernel<<<BN_TOT * T_SEQ, 256, 0, stream>>>(h, ln2g + l * C_DIM, ln2b + l * C_DIM, u_bf);
    gemm_mfma<1, 2><<<dim3(C_DIM / 128, 640, 1), 256, 0, stream>>>(
        u_bf, C_DIM, 0, W1t + (size_t)l * C_DIM * C_DIM, 0, C_DIM, nullptr, midbf, b1 + l * C_DIM, C_DIM, 0);
    gemm_mfma<1, 1><<<dim3(C_DIM / 128, 640, 1), 256, 0, stream>>>(
        midbf, C_DIM, 0, W2t + (size_t)l * C_DIM * C_DIM, 0, C_DIM, h, nullptr, b2 + l * C_DIM, C_DIM, 0);
  }

  gemm_f32<32, 1><<<dim3(1, 81920 / 64), 256, 0, stream>>>(h, Wc1t, x1, c1b, 81920, 32, C_DIM);
  head_kernel<<<(BN_TOT * T_SEQ + 255) / 256, 256, 0, stream>>>(
      x1, bn1g, bn1b, bn1rm, bn1rv, c2W, c2b, bn2g, bn2b, bn2rm, bn2rv, c3W, c3b, d1a, d2a, sca);
  reduce_kernel<<<32, 256, 0, stream>>>(d1a, d2a, sca, (float*)d_out);
}